// Round 3
// baseline (1022.987 us; speedup 1.0000x reference)
//
#include <hip/hip_runtime.h>

#define NROWS 4096
#define NCLASS 50257
#define BLK 256
#define NSPLIT 4
#define QLEN ((NCLASS + NSPLIT - 1) / NSPLIT)   // 12565
#define U 4            // float4s per thread per chunk iteration (16 floats)
#define DEFER_THR 8.0f // skip rescale unless chunk max beats m by > THR

// Stage 1: one block per (row, quarter-row). Online softmax partial (m, l)
// over ~12.5K classes, chunked with deferred rescale. 16384 blocks total:
// 4x the block-level parallelism and 1/4 the per-block serial depth of the
// previous one-block-per-row version — probes the remaining "per-block
// structure" suspect while staying harness-floor-neutral.
__global__ __launch_bounds__(BLK, 6) void ce_part_kernel(
    const float* __restrict__ pred,
    float* __restrict__ mbuf,    // [NSPLIT][NROWS]
    float* __restrict__ lbuf) {  // [NSPLIT][NROWS]
    const int bid = blockIdx.x;
    const int row  = bid >> 2;   // NSPLIT == 4
    const int part = bid & 3;
    const int begin = part * QLEN;
    const int n = ((begin + QLEN) < NCLASS ? QLEN : (NCLASS - begin)); // 12565 or 12562
    const float* __restrict__ p = pred + (size_t)row * NCLASS + begin;
    const int tid = threadIdx.x;

    float m = -3.4e38f;
    float l = 0.0f;

    // Peel scalar head until 16B-aligned (segment base is only 4B-aligned).
    const int head = (int)(((16u - (unsigned)((size_t)p & 15u)) & 15u) >> 2);
    if (tid < head) {
        m = p[tid];
        l = 1.0f;
    }

    const float4* __restrict__ pv = (const float4*)(p + head);
    const int nvec = (n - head) >> 2;        // ~3141 float4s per segment

    const int CHUNK = U * BLK;               // 1024 float4s per block-chunk
    const int nchunk = nvec / CHUNK;         // 3 full chunks

    for (int c = 0; c < nchunk; ++c) {
        const int base = c * CHUNK + tid;

        // (1) batch the loads — 4 independent coalesced 16B loads in flight
        float4 v[U];
        #pragma unroll
        for (int k = 0; k < U; ++k) v[k] = pv[base + k * BLK];

        // (2) chunk max, off the carried chain
        float cm = -3.4e38f;
        #pragma unroll
        for (int k = 0; k < U; ++k) {
            cm = fmaxf(cm,
                       fmaxf(fmaxf(v[k].x, v[k].y), fmaxf(v[k].z, v[k].w)));
        }

        // (3) deferred rescale — rarely taken after the first chunk
        if (cm > m + DEFER_THR) {
            l *= __expf(m - cm);   // first chunk: exp(-inf)=0, l stays 0
            m = cm;
        }

        // (4) 16 independent exps (bounded by e^DEFER_THR), off-chain sum
        float s = 0.0f;
        #pragma unroll
        for (int k = 0; k < U; ++k) {
            s += __expf(v[k].x - m) + __expf(v[k].y - m)
               + __expf(v[k].z - m) + __expf(v[k].w - m);
        }
        l += s;
    }

    // remainder float4s (same deferred scheme)
    for (int i = nchunk * CHUNK + tid; i < nvec; i += BLK) {
        float4 v = pv[i];
        float vm = fmaxf(fmaxf(v.x, v.y), fmaxf(v.z, v.w));
        if (vm > m + DEFER_THR) {
            l *= __expf(m - vm);
            m = vm;
        }
        l += __expf(v.x - m) + __expf(v.y - m)
           + __expf(v.z - m) + __expf(v.w - m);
    }
    // scalar tail (segment length not a multiple of 4)
    for (int j = head + (nvec << 2) + tid; j < n; j += BLK) {
        float x = p[j];
        if (x > m + DEFER_THR) {
            l *= __expf(m - x);
            m = x;
        }
        l += __expf(x - m);
    }

    // wave-level reduce of (m, l) — exact online merge
    #pragma unroll
    for (int off = 32; off > 0; off >>= 1) {
        float om = __shfl_down(m, off, 64);
        float ol = __shfl_down(l, off, 64);
        float nm = fmaxf(m, om);
        l = l * __expf(m - nm) + ol * __expf(om - nm);
        m = nm;
    }

    // cross-wave reduce via LDS (4 waves)
    __shared__ float sm[BLK / 64];
    __shared__ float sl[BLK / 64];
    const int wave = tid >> 6;
    const int lane = tid & 63;
    if (lane == 0) { sm[wave] = m; sl[wave] = l; }
    __syncthreads();

    if (tid == 0) {
        m = sm[0]; l = sl[0];
        #pragma unroll
        for (int w = 1; w < BLK / 64; ++w) {
            float om = sm[w], ol = sl[w];
            float nm = fmaxf(m, om);
            l = l * __expf(m - nm) + ol * __expf(om - nm);
            m = nm;
        }
        mbuf[part * NROWS + row] = m;   // [part][row] layout -> stage-2 reads coalesce
        lbuf[part * NROWS + row] = l;
    }
}

// Stage 2: single block. Per row: merge the 4 partials, gather p[target],
// accumulate the loss; block-reduce; write the scalar (overwrites poisoned
// d_out directly).
__global__ __launch_bounds__(BLK) void ce_finish_kernel(
    const float* __restrict__ pred,
    const int* __restrict__ target,
    const float* __restrict__ mbuf,
    const float* __restrict__ lbuf,
    float* __restrict__ out) {
    const int tid = threadIdx.x;
    float s = 0.0f;
    for (int row = tid; row < NROWS; row += BLK) {
        float m = mbuf[row];
        float l = lbuf[row];
        #pragma unroll
        for (int q = 1; q < NSPLIT; ++q) {
            float om = mbuf[q * NROWS + row];
            float ol = lbuf[q * NROWS + row];
            float nm = fmaxf(m, om);
            l = l * __expf(m - nm) + ol * __expf(om - nm);
            m = nm;
        }
        const int t = target[row];
        s += -(pred[(size_t)row * NCLASS + t] - m - __logf(l));
    }

    #pragma unroll
    for (int off = 32; off > 0; off >>= 1) s += __shfl_down(s, off, 64);

    __shared__ float sw[BLK / 64];
    if ((tid & 63) == 0) sw[tid >> 6] = s;
    __syncthreads();

    if (tid == 0) {
        float t = 0.0f;
        #pragma unroll
        for (int w = 0; w < BLK / 64; ++w) t += sw[w];
        out[0] = t * (1.0f / (float)NROWS);
    }
}

extern "C" void kernel_launch(void* const* d_in, const int* in_sizes, int n_in,
                              void* d_out, int out_size, void* d_ws, size_t ws_size,
                              hipStream_t stream) {
    const float* pred = (const float*)d_in[0];
    const int* target = (const int*)d_in[1];
    float* out = (float*)d_out;
    float* mbuf = (float*)d_ws;                     // [4][4096] floats
    float* lbuf = (float*)d_ws + NSPLIT * NROWS;    // [4][4096] floats (128 KB total)

    ce_part_kernel<<<NROWS * NSPLIT, BLK, 0, stream>>>(pred, mbuf, lbuf);
    ce_finish_kernel<<<1, BLK, 0, stream>>>(pred, target, mbuf, lbuf, out);
}